// Round 1
// baseline (1814.880 us; speedup 1.0000x reference)
//
#include <hip/hip_runtime.h>
#include <math.h>

// Swin window attention, fully fused, fp32 baseline.
// One 256-thread workgroup per window (B_=4096 windows).
// Phases: load x -> QKV GEMM -> per-head (QK^T+bias+mask -> softmax -> PV) -> proj GEMM.

#define NTOK   49      // tokens per window (7x7)
#define CDIM   128     // channels
#define NHEAD  4
#define HDIM   32
#define C3     384     // 3*CDIM
#define NWIN   256     // mask windows
#define QKV_LD 129     // padded LDS stride (odd -> conflict-free K^T reads)
#define BLOCK  256

__global__ __launch_bounds__(BLOCK, 1)
void win_attn_fused(const float* __restrict__ x,
                    const float* __restrict__ mask,
                    const float* __restrict__ qkv_w,
                    const float* __restrict__ qkv_b,
                    const float* __restrict__ proj_w,
                    const float* __restrict__ proj_b,
                    const float* __restrict__ bias_table,
                    float* __restrict__ out) {
    // xa doubles as the attention-output (ao) buffer after QKV phase consumes x.
    __shared__ float xa[NTOK * CDIM];        // 25,088 B
    __shared__ float qs[NTOK * QKV_LD];      // 25,284 B (q, pre-scaled)
    __shared__ float ks_[NTOK * QKV_LD];     // 25,284 B
    __shared__ float vs[NTOK * QKV_LD];      // 25,284 B
    __shared__ float S[NTOK * NTOK];         //  9,604 B   total ~108 KB

    const int b   = blockIdx.x;
    const int tid = threadIdx.x;
    const float scale = 0.17677669529663687f;  // 1/sqrt(32)

    // ---- Phase 0: stage x tile (49x128 = 1568 float4), coalesced ----
    {
        const float4* src = (const float4*)(x + (size_t)b * (NTOK * CDIM));
        float4* dst = (float4*)xa;
        for (int i = tid; i < NTOK * CDIM / 4; i += BLOCK) dst[i] = src[i];
    }
    __syncthreads();

    // ---- Phase 1: qkv = x @ qkv_w + qkv_b -> q(scaled)/k/v in LDS ----
    // Tasks: 7 row-groups x 384 cols = 2688; each task computes 7 rows (reg tile).
    // One global w-load amortized over 7 FMAs; x reads are LDS broadcasts.
    for (int task = tid; task < 7 * C3; task += BLOCK) {
        const int rg = task / C3;   // 0..6
        const int c  = task % C3;   // 0..383
        float acc[7];
        const float bia = qkv_b[c];
        #pragma unroll
        for (int j = 0; j < 7; ++j) acc[j] = bia;
        const float* wcol = qkv_w + c;
        #pragma unroll 4
        for (int k = 0; k < CDIM; ++k) {
            const float wv = wcol[(size_t)k * C3];
            #pragma unroll
            for (int j = 0; j < 7; ++j)
                acc[j] += xa[(rg * 7 + j) * CDIM + k] * wv;
        }
        #pragma unroll
        for (int j = 0; j < 7; ++j) {
            const int n = rg * 7 + j;
            if (c < CDIM)            qs [n * QKV_LD + c]            = acc[j] * scale;
            else if (c < 2 * CDIM)   ks_[n * QKV_LD + (c - CDIM)]   = acc[j];
            else                     vs [n * QKV_LD + (c - 2*CDIM)] = acc[j];
        }
    }

    // ---- Phase 2: per-head attention ----
    const float* mwin = mask + (size_t)(b % NWIN) * (NTOK * NTOK);
    for (int h = 0; h < NHEAD; ++h) {
        __syncthreads();   // qkv ready (h=0) / prev PV done reading S (h>0)

        // S = (q*scale) @ k^T + rel_pos_bias + mask    (2401 entries, dot-32)
        for (int t = tid; t < NTOK * NTOK; t += BLOCK) {
            const int n = t / NTOK, m = t % NTOK;
            const float* qrow = qs  + n * QKV_LD + h * HDIM;
            const float* krow = ks_ + m * QKV_LD + h * HDIM;
            float acc = 0.f;
            #pragma unroll
            for (int d = 0; d < HDIM; ++d) acc += qrow[d] * krow[d];
            const int i0 = n / 7, i1 = n % 7, j0 = m / 7, j1 = m % 7;
            const int ridx = (i0 - j0 + 6) * 13 + (i1 - j1 + 6);
            acc += bias_table[ridx * NHEAD + h];
            acc += mwin[t];
            S[t] = acc;
        }
        __syncthreads();

        // softmax per row (49 rows, one thread each; cheap)
        if (tid < NTOK) {
            float* row = S + tid * NTOK;
            float mx = row[0];
            for (int m = 1; m < NTOK; ++m) mx = fmaxf(mx, row[m]);
            float sum = 0.f;
            for (int m = 0; m < NTOK; ++m) { const float e = expf(row[m] - mx); sum += e; row[m] = e; }
            const float inv = 1.f / sum;
            for (int m = 0; m < NTOK; ++m) row[m] *= inv;
        }
        __syncthreads();

        // PV: ao[n][h*32+d] = S @ v_h   (1568 entries, dot-49)
        for (int t = tid; t < NTOK * HDIM; t += BLOCK) {
            const int n = t / HDIM, d = t % HDIM;
            const float* srow = S + n * NTOK;
            const float* vcol = vs + h * HDIM + d;
            float acc = 0.f;
            #pragma unroll
            for (int m = 0; m < NTOK; ++m) acc += srow[m] * vcol[m * QKV_LD];
            xa[n * CDIM + h * HDIM + d] = acc;   // xa now = attention output
        }
    }
    __syncthreads();

    // ---- Phase 3: out = ao @ proj_w + proj_b ----
    // Tasks: 7 row-groups x 128 cols = 896; 7-row register tile like phase 1.
    float* orow = out + (size_t)b * (NTOK * CDIM);
    for (int task = tid; task < 7 * CDIM; task += BLOCK) {
        const int rg = task / CDIM;
        const int c  = task % CDIM;
        float acc[7];
        const float pb = proj_b[c];
        #pragma unroll
        for (int j = 0; j < 7; ++j) acc[j] = pb;
        const float* wcol = proj_w + c;
        #pragma unroll 4
        for (int k = 0; k < CDIM; ++k) {
            const float wv = wcol[(size_t)k * CDIM];
            #pragma unroll
            for (int j = 0; j < 7; ++j)
                acc[j] += xa[(rg * 7 + j) * CDIM + k] * wv;
        }
        #pragma unroll
        for (int j = 0; j < 7; ++j)
            orow[(rg * 7 + j) * CDIM + c] = acc[j];
    }
}

extern "C" void kernel_launch(void* const* d_in, const int* in_sizes, int n_in,
                              void* d_out, int out_size, void* d_ws, size_t ws_size,
                              hipStream_t stream) {
    const float* x          = (const float*)d_in[0];
    const float* mask       = (const float*)d_in[1];
    const float* qkv_w      = (const float*)d_in[2];
    const float* qkv_b      = (const float*)d_in[3];
    const float* proj_w     = (const float*)d_in[4];
    const float* proj_b     = (const float*)d_in[5];
    const float* bias_table = (const float*)d_in[6];
    float* out = (float*)d_out;

    hipLaunchKernelGGL(win_attn_fused, dim3(4096), dim3(BLOCK), 0, stream,
                       x, mask, qkv_w, qkv_b, proj_w, proj_b, bias_table, out);
}